// Round 1
// baseline (642.492 us; speedup 1.0000x reference)
//
#include <hip/hip_runtime.h>
#include <math.h>

// Problem constants (reference: B=2, S=2048, DIM=512, NUM_HEADS=8, HEAD_DIM=64)
#define S_LEN 2048

// ---------------------------------------------------------------------------
// Kernel 1: fused QKV projection.
//   C[4096,1536] = concat(x_real,x_imag)[4096,1024] @ [Wq|Wk|Wv] + bias
// Tile: 64x64 per block (one head's 64 cols exactly), 256 threads, 4x4/thread.
// Epilogue: per-row softmax over the 64 head cols (Q,K) + sqrt; V bias only.
// Output scattered to [B,H,S,64] layout for the attention kernel.
// ---------------------------------------------------------------------------
__global__ __launch_bounds__(256) void qkv_kernel(
    const float* __restrict__ xr, const float* __restrict__ xi,
    const float* __restrict__ Wq, const float* __restrict__ bq,
    const float* __restrict__ Wk, const float* __restrict__ bk,
    const float* __restrict__ Wv, const float* __restrict__ bv,
    float* __restrict__ spO, float* __restrict__ sqO, float* __restrict__ vvO)
{
    __shared__ float smem[4352];          // As[64][36] + Bs[32][64] = 2304+2048
    float* As = smem;                     // [m][k] stride 36 (pad breaks banks)
    float* Bs = smem + 2304;              // [k][n] stride 64
    float* Cs = smem;                     // epilogue view [64][68] = 4352 exactly

    const int nt = blockIdx.x;            // 0..23 : which 64-col tile of 1536
    const int mt = blockIdx.y;            // 0..63 : which 64-row tile of 4096
    const int iw = nt >> 3;               // 0=Q,1=K,2=V
    const int n0 = (nt & 7) << 6;         // col offset within the 512-wide W
    const int m0 = mt << 6;

    const float* W    = (iw == 0) ? Wq : (iw == 1) ? Wk : Wv;
    const float* bias = (iw == 0) ? bq : (iw == 1) ? bk : bv;

    const int tid = threadIdx.x;
    const int tx = tid & 15, ty = tid >> 4;

    float acc[4][4] = {};

    for (int k0 = 0; k0 < 1024; k0 += 32) {
        // A-tile: rows m0..m0+63, k in [k0,k0+32). k<512 -> x_real else x_imag.
        const float* src = (k0 < 512) ? xr : xi;
        const int kk = k0 & 511;
        #pragma unroll
        for (int rep = 0; rep < 2; ++rep) {
            int q = tid + rep * 256;                 // 512 float4 total
            int r = q >> 3, c4 = (q & 7) << 2;
            float4 t = *(const float4*)(src + (size_t)(m0 + r) * 512 + kk + c4);
            As[r * 36 + c4 + 0] = t.x;
            As[r * 36 + c4 + 1] = t.y;
            As[r * 36 + c4 + 2] = t.z;
            As[r * 36 + c4 + 3] = t.w;
        }
        // B-tile: W rows k0..k0+31, cols n0..n0+63 (row-major stride 512)
        #pragma unroll
        for (int rep = 0; rep < 2; ++rep) {
            int q = tid + rep * 256;
            int r = q >> 4, c4 = (q & 15) << 2;
            float4 t = *(const float4*)(W + (size_t)(k0 + r) * 512 + n0 + c4);
            *(float4*)&Bs[r * 64 + c4] = t;
        }
        __syncthreads();
        #pragma unroll
        for (int kg = 0; kg < 32; kg += 4) {
            float4 a[4], b[4];
            #pragma unroll
            for (int i = 0; i < 4; ++i)
                a[i] = *(const float4*)&As[(ty * 4 + i) * 36 + kg];
            #pragma unroll
            for (int k2 = 0; k2 < 4; ++k2)
                b[k2] = *(const float4*)&Bs[(kg + k2) * 64 + tx * 4];
            #pragma unroll
            for (int i = 0; i < 4; ++i) {
                const float* ap = (const float*)&a[i];
                #pragma unroll
                for (int k2 = 0; k2 < 4; ++k2) {
                    const float* bp = (const float*)&b[k2];
                    #pragma unroll
                    for (int j = 0; j < 4; ++j)
                        acc[i][j] = fmaf(ap[k2], bp[j], acc[i][j]);
                }
            }
        }
        __syncthreads();
    }

    // Epilogue: +bias into Cs, then per-row softmax(64)+sqrt for Q/K.
    #pragma unroll
    for (int i = 0; i < 4; ++i)
        #pragma unroll
        for (int j = 0; j < 4; ++j)
            Cs[(ty * 4 + i) * 68 + tx * 4 + j] = acc[i][j] + bias[n0 + tx * 4 + j];
    __syncthreads();

    if (iw < 2 && tid < 64) {
        float mx = -1e30f;
        for (int c = 0; c < 64; ++c) mx = fmaxf(mx, Cs[tid * 68 + c]);
        float s = 0.f;
        for (int c = 0; c < 64; ++c) {
            float e = __expf(Cs[tid * 68 + c] - mx);
            Cs[tid * 68 + c] = e;
            s += e;
        }
        float inv = 1.0f / s;
        for (int c = 0; c < 64; ++c)
            Cs[tid * 68 + c] = sqrtf(Cs[tid * 68 + c] * inv);
    }
    __syncthreads();

    float* dst = (iw == 0) ? spO : (iw == 1) ? sqO : vvO;
    const int h = n0 >> 6;
    for (int q = tid; q < 4096; q += 256) {
        int row = q >> 6, d = q & 63;
        int r = m0 + row;
        int b = r >> 11;                    // r / 2048
        int s = r & 2047;
        dst[(((size_t)(b * 8 + h)) * S_LEN + s) * 64 + d] = Cs[row * 68 + d];
    }
}

// ---------------------------------------------------------------------------
// Kernel 2: flash-style attention per (b,h).
//   bc = sp @ sq^T (K=64), dist=acos(clip(bc)), w=exp(-dist^2)  [w<=1, no max]
//   attended = (w @ V) / rowsum(w)
// Block: 64 Q-rows, loop over 32 j-tiles of 64. 256 threads, 4x4/thread.
// ---------------------------------------------------------------------------
__global__ __launch_bounds__(256) void attn_kernel(
    const float* __restrict__ sp, const float* __restrict__ sq,
    const float* __restrict__ vv, float* __restrict__ att)
{
    __shared__ float spS[64 * 68];   // [m][d]
    __shared__ float sqT[64 * 68];   // [d][j] for bc; reused as Vs[j][d] for PV
    __shared__ float Ps[64 * 68];    // [m][j] probabilities
    __shared__ float denS[64];

    const int bh = blockIdx.y;                 // 0..15
    const int m0 = blockIdx.x << 6;            // Q-row tile base
    const size_t base = (size_t)bh * (S_LEN * 64);
    const float* spB = sp + base;
    const float* sqB = sq + base;
    const float* vB  = vv + base;

    const int tid = threadIdx.x;
    const int tx = tid & 15, ty = tid >> 4;

    // stage sp tile once: 64x64, [m][d] stride 68 (aligned float4 stores)
    for (int q = tid; q < 1024; q += 256) {
        int r = q >> 4, c4 = (q & 15) << 2;
        float4 t = *(const float4*)(spB + (size_t)(m0 + r) * 64 + c4);
        *(float4*)&spS[r * 68 + c4] = t;
    }

    float acc[4][4] = {};
    float den[4] = {0.f, 0.f, 0.f, 0.f};

    for (int jt = 0; jt < 32; ++jt) {
        const int j0 = jt << 6;
        __syncthreads();   // prev iter's PV reads of sqT/Ps complete
        // stage sq tile TRANSPOSED: sqT[d][j]
        for (int q = tid; q < 1024; q += 256) {
            int r = q >> 4, c4 = (q & 15) << 2;
            float4 t = *(const float4*)(sqB + (size_t)(j0 + r) * 64 + c4);
            sqT[(c4 + 0) * 68 + r] = t.x;
            sqT[(c4 + 1) * 68 + r] = t.y;
            sqT[(c4 + 2) * 68 + r] = t.z;
            sqT[(c4 + 3) * 68 + r] = t.w;
        }
        __syncthreads();

        // bc = sp @ sq^T over d=64
        float p[4][4] = {};
        #pragma unroll 4
        for (int d0 = 0; d0 < 64; d0 += 4) {
            float4 a[4], b[4];
            #pragma unroll
            for (int i = 0; i < 4; ++i)
                a[i] = *(const float4*)&spS[(ty * 4 + i) * 68 + d0];
            #pragma unroll
            for (int dd = 0; dd < 4; ++dd)
                b[dd] = *(const float4*)&sqT[(d0 + dd) * 68 + tx * 4];
            #pragma unroll
            for (int i = 0; i < 4; ++i) {
                const float* ap = (const float*)&a[i];
                #pragma unroll
                for (int dd = 0; dd < 4; ++dd) {
                    const float* bp = (const float*)&b[dd];
                    #pragma unroll
                    for (int j = 0; j < 4; ++j)
                        p[i][j] = fmaf(ap[dd], bp[j], p[i][j]);
                }
            }
        }

        // transform: clip -> acos -> exp(-dist^2); accumulate denominator
        #pragma unroll
        for (int i = 0; i < 4; ++i)
            #pragma unroll
            for (int j = 0; j < 4; ++j) {
                float bc = fminf(1.0f, fmaxf(-1.0f, p[i][j]));
                float dg = acosf(bc);
                float e = __expf(-dg * dg);
                p[i][j] = e;
                den[i] += e;
            }

        __syncthreads();   // everyone done reading sqT before V overwrites it
        // store P; stage V tile (natural [j][d]) into sqT buffer
        #pragma unroll
        for (int i = 0; i < 4; ++i)
            #pragma unroll
            for (int j = 0; j < 4; ++j)
                Ps[(ty * 4 + i) * 68 + tx * 4 + j] = p[i][j];
        for (int q = tid; q < 1024; q += 256) {
            int r = q >> 4, c4 = (q & 15) << 2;
            float4 t = *(const float4*)(vB + (size_t)(j0 + r) * 64 + c4);
            *(float4*)&sqT[r * 68 + c4] = t;
        }
        __syncthreads();

        // acc += P @ V over j=64
        #pragma unroll 4
        for (int jj0 = 0; jj0 < 64; jj0 += 4) {
            float4 a[4], b[4];
            #pragma unroll
            for (int i = 0; i < 4; ++i)
                a[i] = *(const float4*)&Ps[(ty * 4 + i) * 68 + jj0];
            #pragma unroll
            for (int dd = 0; dd < 4; ++dd)
                b[dd] = *(const float4*)&sqT[(jj0 + dd) * 68 + tx * 4];
            #pragma unroll
            for (int i = 0; i < 4; ++i) {
                const float* ap = (const float*)&a[i];
                #pragma unroll
                for (int dd = 0; dd < 4; ++dd) {
                    const float* bp = (const float*)&b[dd];
                    #pragma unroll
                    for (int j = 0; j < 4; ++j)
                        acc[i][j] = fmaf(ap[dd], bp[j], acc[i][j]);
                }
            }
        }
    }

    // reduce den across the 16 tx threads sharing each row (reuse spS)
    __syncthreads();
    #pragma unroll
    for (int i = 0; i < 4; ++i)
        spS[(ty * 4 + i) * 16 + tx] = den[i];
    __syncthreads();
    if (tid < 64) {
        float s = 0.f;
        for (int t = 0; t < 16; ++t) s += spS[tid * 16 + t];
        denS[tid] = 1.0f / s;
    }
    __syncthreads();

    const int b = bh >> 3, h = bh & 7;
    #pragma unroll
    for (int i = 0; i < 4; ++i) {
        float inv = denS[ty * 4 + i];
        float4 o;
        o.x = acc[i][0] * inv;
        o.y = acc[i][1] * inv;
        o.z = acc[i][2] * inv;
        o.w = acc[i][3] * inv;
        // attended layout [B,S,512], col = h*64 + d
        *(float4*)(att + ((size_t)b * S_LEN + (m0 + ty * 4 + i)) * 512 + h * 64 + tx * 4) = o;
    }
}

// ---------------------------------------------------------------------------
// Kernel 3: output projection. out[4096,1024] = att[4096,512] @ Wo + bo
// ---------------------------------------------------------------------------
__global__ __launch_bounds__(256) void out_kernel(
    const float* __restrict__ att, const float* __restrict__ Wo,
    const float* __restrict__ bo, float* __restrict__ out)
{
    __shared__ float smem[4352];
    float* As = smem;                 // [64][36]
    float* Bs = smem + 2304;          // [32][64]

    const int n0 = blockIdx.x << 6;   // 0..15 tiles of 1024
    const int m0 = blockIdx.y << 6;   // 0..63 tiles of 4096

    const int tid = threadIdx.x;
    const int tx = tid & 15, ty = tid >> 4;

    float acc[4][4] = {};

    for (int k0 = 0; k0 < 512; k0 += 32) {
        #pragma unroll
        for (int rep = 0; rep < 2; ++rep) {
            int q = tid + rep * 256;
            int r = q >> 3, c4 = (q & 7) << 2;
            float4 t = *(const float4*)(att + (size_t)(m0 + r) * 512 + k0 + c4);
            As[r * 36 + c4 + 0] = t.x;
            As[r * 36 + c4 + 1] = t.y;
            As[r * 36 + c4 + 2] = t.z;
            As[r * 36 + c4 + 3] = t.w;
        }
        #pragma unroll
        for (int rep = 0; rep < 2; ++rep) {
            int q = tid + rep * 256;
            int r = q >> 4, c4 = (q & 15) << 2;
            float4 t = *(const float4*)(Wo + (size_t)(k0 + r) * 1024 + n0 + c4);
            *(float4*)&Bs[r * 64 + c4] = t;
        }
        __syncthreads();
        #pragma unroll
        for (int kg = 0; kg < 32; kg += 4) {
            float4 a[4], b[4];
            #pragma unroll
            for (int i = 0; i < 4; ++i)
                a[i] = *(const float4*)&As[(ty * 4 + i) * 36 + kg];
            #pragma unroll
            for (int k2 = 0; k2 < 4; ++k2)
                b[k2] = *(const float4*)&Bs[(kg + k2) * 64 + tx * 4];
            #pragma unroll
            for (int i = 0; i < 4; ++i) {
                const float* ap = (const float*)&a[i];
                #pragma unroll
                for (int k2 = 0; k2 < 4; ++k2) {
                    const float* bp = (const float*)&b[k2];
                    #pragma unroll
                    for (int j = 0; j < 4; ++j)
                        acc[i][j] = fmaf(ap[k2], bp[j], acc[i][j]);
                }
            }
        }
        __syncthreads();
    }

    #pragma unroll
    for (int i = 0; i < 4; ++i) {
        float4 o;
        o.x = acc[i][0] + bo[n0 + tx * 4 + 0];
        o.y = acc[i][1] + bo[n0 + tx * 4 + 1];
        o.z = acc[i][2] + bo[n0 + tx * 4 + 2];
        o.w = acc[i][3] + bo[n0 + tx * 4 + 3];
        *(float4*)(out + (size_t)(m0 + ty * 4 + i) * 1024 + n0 + tx * 4) = o;
    }
}

extern "C" void kernel_launch(void* const* d_in, const int* in_sizes, int n_in,
                              void* d_out, int out_size, void* d_ws, size_t ws_size,
                              hipStream_t stream) {
    const float* xr = (const float*)d_in[0];
    const float* xi = (const float*)d_in[1];
    const float* Wq = (const float*)d_in[2];
    const float* bq = (const float*)d_in[3];
    const float* Wk = (const float*)d_in[4];
    const float* bk = (const float*)d_in[5];
    const float* Wv = (const float*)d_in[6];
    const float* bv = (const float*)d_in[7];
    const float* Wo = (const float*)d_in[8];
    const float* bo = (const float*)d_in[9];
    float* out = (float*)d_out;

    // workspace: sp, sq, v in [B,H,S,64] + attended [B,S,512] (8 MB each)
    float* ws  = (float*)d_ws;
    float* sp  = ws;
    float* sq  = ws + 2097152;
    float* vv  = ws + 2 * 2097152;
    float* att = ws + 3 * 2097152;

    hipLaunchKernelGGL(qkv_kernel, dim3(24, 64), dim3(256), 0, stream,
                       xr, xi, Wq, bq, Wk, bk, Wv, bv, sp, sq, vv);
    hipLaunchKernelGGL(attn_kernel, dim3(32, 16), dim3(256), 0, stream,
                       sp, sq, vv, att);
    hipLaunchKernelGGL(out_kernel, dim3(16, 64), dim3(256), 0, stream,
                       att, Wo, bo, out);
}

// Round 2
// 327.152 us; speedup vs baseline: 1.9639x; 1.9639x over previous
//
#include <hip/hip_runtime.h>
#include <math.h>

// GeoAttention on gfx950: B=2, S=2048, DIM=512, H=8, HD=64.
// All GEMM stages on bf16 MFMA (16x16x32), fp32 accumulate, no LDS in the
// GEMM main loops (operands read as contiguous 16B frags from global bf16).

typedef __attribute__((ext_vector_type(8))) short short8;
typedef __attribute__((ext_vector_type(4))) float f32x4;

#define MFMA(a, b, c) __builtin_amdgcn_mfma_f32_16x16x32_bf16((a), (b), (c), 0, 0, 0)

static __device__ __forceinline__ short f2bf(float f) {
    unsigned u = __float_as_uint(f);
    u += 0x7fffu + ((u >> 16) & 1u);          // round-to-nearest-even
    return (short)(u >> 16);
}

// ---------------------------------------------------------------------------
// Prep 1: xb[4096][1024] bf16 = concat(x_real, x_imag)
// ---------------------------------------------------------------------------
__global__ __launch_bounds__(256) void convert_x(
    const float* __restrict__ xr, const float* __restrict__ xi,
    short* __restrict__ xb)
{
    int idx = blockIdx.x * 256 + threadIdx.x;   // 1,048,576 threads
    int e = idx << 2;
    int m = e >> 10, k = e & 1023;
    const float* src = (k < 512) ? xr : xi;
    float4 t = *(const float4*)(src + (size_t)m * 512 + (k & 511));
    unsigned lo = (unsigned short)f2bf(t.x) | ((unsigned)(unsigned short)f2bf(t.y) << 16);
    unsigned hi = (unsigned short)f2bf(t.z) | ((unsigned)(unsigned short)f2bf(t.w) << 16);
    uint2 o; o.x = lo; o.y = hi;
    *(uint2*)(xb + e) = o;
}

// ---------------------------------------------------------------------------
// Prep 2: transpose + convert weights to bf16, n-major [N][K].
//   z=0,1,2: Wq/Wk/Wv [1024][512] -> [512][1024]; z=3: Wo [512][1024] -> [1024][512]
// ---------------------------------------------------------------------------
__global__ __launch_bounds__(256) void transpose_w(
    const float* __restrict__ Wq, const float* __restrict__ Wk,
    const float* __restrict__ Wv, const float* __restrict__ Wo,
    short* __restrict__ wqt, short* __restrict__ wkt,
    short* __restrict__ wvt, short* __restrict__ wot)
{
    __shared__ float t[32][33];
    const int z = blockIdx.z;
    const float* src = (z == 0) ? Wq : (z == 1) ? Wk : (z == 2) ? Wv : Wo;
    short* dst = (z == 0) ? wqt : (z == 1) ? wkt : (z == 2) ? wvt : wot;
    const int K = (z < 3) ? 1024 : 512;
    const int N = (z < 3) ? 512 : 1024;
    const int n0 = blockIdx.x << 5, k0 = blockIdx.y << 5;
    if (n0 >= N || k0 >= K) return;
    const int tx = threadIdx.x & 31, ty = threadIdx.x >> 5;
    #pragma unroll
    for (int i = 0; i < 4; ++i)
        t[ty + 8 * i][tx] = src[(size_t)(k0 + ty + 8 * i) * N + n0 + tx];
    __syncthreads();
    #pragma unroll
    for (int i = 0; i < 4; ++i)
        dst[(size_t)(n0 + ty + 8 * i) * K + k0 + tx] = f2bf(t[tx][ty + 8 * i]);
}

// ---------------------------------------------------------------------------
// Kernel 1: QKV projection, bf16 MFMA, fused softmax(d=64)+sqrt epilogue.
// Grid (24, 32): blockIdx.x = iw*8+h (iw: 0=Q,1=K,2=V), blockIdx.y = 128-row tile.
// Block 256 = 4 waves; wave = 32 rows x 64 cols (2 row-strips, 4 col-tiles).
// Q/K -> sp/sq [b,h,s,d] bf16; V -> vt [b,h,d,s] bf16 (transposed for PV frags).
// ---------------------------------------------------------------------------
__global__ __launch_bounds__(256) void qkv_mfma(
    const short* __restrict__ xb,
    const short* __restrict__ wqt, const short* __restrict__ wkt,
    const short* __restrict__ wvt,
    const float* __restrict__ bq, const float* __restrict__ bk,
    const float* __restrict__ bv,
    short* __restrict__ sp, short* __restrict__ sq, short* __restrict__ vt)
{
    const int iwb = blockIdx.x;
    const int iw = iwb >> 3;
    const int h  = iwb & 7;
    const int m0 = blockIdx.y << 7;
    const int tid = threadIdx.x;
    const int w = tid >> 6, lane = tid & 63;
    const int l = lane & 15, quad = lane >> 4;

    const short* wt   = (iw == 0) ? wqt : (iw == 1) ? wkt : wvt;
    const float* bias = (iw == 0) ? bq  : (iw == 1) ? bk  : bv;
    short* dst        = (iw == 0) ? sp  : (iw == 1) ? sq  : vt;

    const short* a0p = xb + (size_t)(m0 + w * 32 + l) * 1024 + quad * 8;
    const short* a1p = a0p + 16 * 1024;
    const short* bp0 = wt + (size_t)(h * 64 +  0 + l) * 1024 + quad * 8;
    const short* bp1 = wt + (size_t)(h * 64 + 16 + l) * 1024 + quad * 8;
    const short* bp2 = wt + (size_t)(h * 64 + 32 + l) * 1024 + quad * 8;
    const short* bp3 = wt + (size_t)(h * 64 + 48 + l) * 1024 + quad * 8;

    const f32x4 z4 = {0.f, 0.f, 0.f, 0.f};
    f32x4 acc[2][4];
    #pragma unroll
    for (int i = 0; i < 2; ++i)
        #pragma unroll
        for (int j = 0; j < 4; ++j) acc[i][j] = z4;

    for (int kc = 0; kc < 32; ++kc) {
        const int ko = kc * 32;
        short8 a0 = *(const short8*)(a0p + ko);
        short8 a1 = *(const short8*)(a1p + ko);
        short8 b0 = *(const short8*)(bp0 + ko);
        short8 b1 = *(const short8*)(bp1 + ko);
        short8 b2 = *(const short8*)(bp2 + ko);
        short8 b3 = *(const short8*)(bp3 + ko);
        acc[0][0] = MFMA(a0, b0, acc[0][0]);
        acc[1][0] = MFMA(a1, b0, acc[1][0]);
        acc[0][1] = MFMA(a0, b1, acc[0][1]);
        acc[1][1] = MFMA(a1, b1, acc[1][1]);
        acc[0][2] = MFMA(a0, b2, acc[0][2]);
        acc[1][2] = MFMA(a1, b2, acc[1][2]);
        acc[0][3] = MFMA(a0, b3, acc[0][3]);
        acc[1][3] = MFMA(a1, b3, acc[1][3]);
    }

    float bcol[4];
    #pragma unroll
    for (int nt = 0; nt < 4; ++nt) bcol[nt] = bias[h * 64 + nt * 16 + l];

    #pragma unroll
    for (int r16 = 0; r16 < 2; ++r16) {
        #pragma unroll
        for (int reg = 0; reg < 4; ++reg) {
            const int sg = m0 + w * 32 + r16 * 16 + quad * 4 + reg;  // global row
            const int b = sg >> 11, s = sg & 2047;
            float v[4];
            #pragma unroll
            for (int nt = 0; nt < 4; ++nt) v[nt] = acc[r16][nt][reg] + bcol[nt];
            if (iw < 2) {
                // row softmax over 64 cols (4 tiles x 16 lanes of this quad)
                float mx = fmaxf(fmaxf(v[0], v[1]), fmaxf(v[2], v[3]));
                #pragma unroll
                for (int msk = 1; msk < 16; msk <<= 1) mx = fmaxf(mx, __shfl_xor(mx, msk));
                float e[4], ssum = 0.f;
                #pragma unroll
                for (int nt = 0; nt < 4; ++nt) { e[nt] = __expf(v[nt] - mx); ssum += e[nt]; }
                #pragma unroll
                for (int msk = 1; msk < 16; msk <<= 1) ssum += __shfl_xor(ssum, msk);
                float inv = 1.0f / ssum;
                short* o = dst + ((size_t)(b * 8 + h) * 2048 + s) * 64 + l;
                #pragma unroll
                for (int nt = 0; nt < 4; ++nt)
                    o[nt * 16] = f2bf(sqrtf(e[nt] * inv));
            } else {
                // V: transposed store vt[b,h,d,s]
                short* o = vt + ((size_t)(b * 8 + h) * 64 + l) * 2048 + s;
                #pragma unroll
                for (int nt = 0; nt < 4; ++nt)
                    o[(size_t)nt * 16 * 2048] = f2bf(v[nt]);
            }
        }
    }
}

// ---------------------------------------------------------------------------
// Kernel 2: attention. Grid (32, 16): 64 Q-rows per block, bh = blockIdx.y.
// Wave = 16 Q-rows x full S sweep. No __syncthreads in the jt loop:
// P's C->A layout transform uses wave-private LDS.
// ---------------------------------------------------------------------------
__global__ __launch_bounds__(256) void attn_mfma(
    const short* __restrict__ sp, const short* __restrict__ sq,
    const short* __restrict__ vt, short* __restrict__ attB)
{
    __shared__ float Pb[4][16 * 68];            // per-wave 16x64 (+4 pad) fp32
    const int m0 = blockIdx.x << 6;
    const int bh = blockIdx.y;
    const int tid = threadIdx.x;
    const int w = tid >> 6, lane = tid & 63;
    const int l = lane & 15, quad = lane >> 4;

    const short* spB = sp + (size_t)bh * 2048 * 64;
    const short* sqB = sq + (size_t)bh * 2048 * 64;
    const short* vtB = vt + (size_t)bh * 64 * 2048;
    float* P = &Pb[w][0];

    const short* ap = spB + (size_t)(m0 + w * 16 + l) * 64 + quad * 8;
    short8 asp0 = *(const short8*)(ap);
    short8 asp1 = *(const short8*)(ap + 32);

    const f32x4 z4 = {0.f, 0.f, 0.f, 0.f};
    f32x4 acc[4] = {z4, z4, z4, z4};
    float den[4] = {0.f, 0.f, 0.f, 0.f};

    for (int jt = 0; jt < 32; ++jt) {
        const short* sqj = sqB + (size_t)(jt * 64) * 64;
        #pragma unroll
        for (int nt = 0; nt < 4; ++nt) {
            const short* q = sqj + (size_t)(nt * 16 + l) * 64 + quad * 8;
            short8 b0 = *(const short8*)(q);
            short8 b1 = *(const short8*)(q + 32);
            f32x4 p = MFMA(asp0, b0, z4);
            p = MFMA(asp1, b1, p);
            #pragma unroll
            for (int reg = 0; reg < 4; ++reg) {
                float x = fminf(1.f, fmaxf(-1.f, p[reg]));
                float xa = fabsf(x);
                float t = sqrtf(1.f - xa);
                float pl = fmaf(fmaf(fmaf(-0.0187293f, xa, 0.0742610f),
                                     xa, -0.2121144f), xa, 1.5707288f);
                float d = t * pl;                       // acos(|x|), |err|<7e-5
                d = (x < 0.f) ? 3.14159265f - d : d;
                float wv = __expf(-d * d);
                den[reg] += wv;
                P[(quad * 4 + reg) * 68 + nt * 16 + l] = wv;
            }
        }
        // P: C-layout (LDS) -> A-layout frags, bf16
        short8 pa0, pa1;
        {
            const float* pr = P + l * 68 + quad * 8;
            float4 f0 = *(const float4*)(pr);
            float4 f1 = *(const float4*)(pr + 4);
            float4 f2 = *(const float4*)(pr + 32);
            float4 f3 = *(const float4*)(pr + 36);
            pa0[0] = f2bf(f0.x); pa0[1] = f2bf(f0.y); pa0[2] = f2bf(f0.z); pa0[3] = f2bf(f0.w);
            pa0[4] = f2bf(f1.x); pa0[5] = f2bf(f1.y); pa0[6] = f2bf(f1.z); pa0[7] = f2bf(f1.w);
            pa1[0] = f2bf(f2.x); pa1[1] = f2bf(f2.y); pa1[2] = f2bf(f2.z); pa1[3] = f2bf(f2.w);
            pa1[4] = f2bf(f3.x); pa1[5] = f2bf(f3.y); pa1[6] = f2bf(f3.z); pa1[7] = f2bf(f3.w);
        }
        const short* vj = vtB + jt * 64;
        #pragma unroll
        for (int nt = 0; nt < 4; ++nt) {
            const short* q = vj + (size_t)(nt * 16 + l) * 2048 + quad * 8;
            short8 b0 = *(const short8*)(q);
            short8 b1 = *(const short8*)(q + 32);
            acc[nt] = MFMA(pa0, b0, acc[nt]);
            acc[nt] = MFMA(pa1, b1, acc[nt]);
        }
    }

    #pragma unroll
    for (int reg = 0; reg < 4; ++reg) {
        float s = den[reg];
        #pragma unroll
        for (int msk = 1; msk < 16; msk <<= 1) s += __shfl_xor(s, msk);
        den[reg] = 1.0f / s;
    }

    const int b = bh >> 3, hh = bh & 7;
    #pragma unroll
    for (int nt = 0; nt < 4; ++nt)
        #pragma unroll
        for (int reg = 0; reg < 4; ++reg) {
            const int srow = m0 + w * 16 + quad * 4 + reg;
            attB[((size_t)(b * 2048 + srow)) * 512 + hh * 64 + nt * 16 + l] =
                f2bf(acc[nt][reg] * den[reg]);
        }
}

// ---------------------------------------------------------------------------
// Kernel 3: out = attB[4096][512](bf16) @ Wo + bo -> fp32 [4096][1024]
// Grid (16, 32): 64-col x 128-row tiles; wave = 32 rows x 64 cols.
// ---------------------------------------------------------------------------
__global__ __launch_bounds__(256) void out_mfma(
    const short* __restrict__ attB, const short* __restrict__ wot,
    const float* __restrict__ bo, float* __restrict__ out)
{
    const int n0 = blockIdx.x << 6;
    const int m0 = blockIdx.y << 7;
    const int tid = threadIdx.x;
    const int w = tid >> 6, lane = tid & 63;
    const int l = lane & 15, quad = lane >> 4;

    const short* a0p = attB + (size_t)(m0 + w * 32 + l) * 512 + quad * 8;
    const short* a1p = a0p + 16 * 512;
    const short* bp0 = wot + (size_t)(n0 +  0 + l) * 512 + quad * 8;
    const short* bp1 = wot + (size_t)(n0 + 16 + l) * 512 + quad * 8;
    const short* bp2 = wot + (size_t)(n0 + 32 + l) * 512 + quad * 8;
    const short* bp3 = wot + (size_t)(n0 + 48 + l) * 512 + quad * 8;

    const f32x4 z4 = {0.f, 0.f, 0.f, 0.f};
    f32x4 acc[2][4];
    #pragma unroll
    for (int i = 0; i < 2; ++i)
        #pragma unroll
        for (int j = 0; j < 4; ++j) acc[i][j] = z4;

    for (int kc = 0; kc < 16; ++kc) {
        const int ko = kc * 32;
        short8 a0 = *(const short8*)(a0p + ko);
        short8 a1 = *(const short8*)(a1p + ko);
        short8 b0 = *(const short8*)(bp0 + ko);
        short8 b1 = *(const short8*)(bp1 + ko);
        short8 b2 = *(const short8*)(bp2 + ko);
        short8 b3 = *(const short8*)(bp3 + ko);
        acc[0][0] = MFMA(a0, b0, acc[0][0]);
        acc[1][0] = MFMA(a1, b0, acc[1][0]);
        acc[0][1] = MFMA(a0, b1, acc[0][1]);
        acc[1][1] = MFMA(a1, b1, acc[1][1]);
        acc[0][2] = MFMA(a0, b2, acc[0][2]);
        acc[1][2] = MFMA(a1, b2, acc[1][2]);
        acc[0][3] = MFMA(a0, b3, acc[0][3]);
        acc[1][3] = MFMA(a1, b3, acc[1][3]);
    }

    #pragma unroll
    for (int r16 = 0; r16 < 2; ++r16)
        #pragma unroll
        for (int reg = 0; reg < 4; ++reg) {
            const int m = m0 + w * 32 + r16 * 16 + quad * 4 + reg;
            float* o = out + (size_t)m * 1024 + n0 + l;
            #pragma unroll
            for (int nt = 0; nt < 4; ++nt)
                o[nt * 16] = acc[r16][nt][reg] + bo[n0 + nt * 16 + l];
        }
}

// ---------------------------------------------------------------------------
extern "C" void kernel_launch(void* const* d_in, const int* in_sizes, int n_in,
                              void* d_out, int out_size, void* d_ws, size_t ws_size,
                              hipStream_t stream) {
    const float* xr = (const float*)d_in[0];
    const float* xi = (const float*)d_in[1];
    const float* Wq = (const float*)d_in[2];
    const float* bq = (const float*)d_in[3];
    const float* Wk = (const float*)d_in[4];
    const float* bk = (const float*)d_in[5];
    const float* Wv = (const float*)d_in[6];
    const float* bv = (const float*)d_in[7];
    const float* Wo = (const float*)d_in[8];
    const float* bo = (const float*)d_in[9];
    float* out = (float*)d_out;

    // ws layout (bf16 elements, all 16B-aligned):
    short* base = (short*)d_ws;
    short* xb   = base;                      // 4096*1024          = 4,194,304
    short* wqt  = xb  + 4194304;             // 512*1024
    short* wkt  = wqt + 524288;
    short* wvt  = wkt + 524288;
    short* wot  = wvt + 524288;              // 1024*512
    short* spW  = wot + 524288;              // 16*2048*64 = 2,097,152
    short* sqW  = spW + 2097152;
    short* vtW  = sqW + 2097152;             // [b,h,d,s]
    short* attB = vtW + 2097152;             // 4096*512
    // total = 14,680,064 shorts = 28 MB

    hipLaunchKernelGGL(convert_x, dim3(4096), dim3(256), 0, stream, xr, xi, xb);
    hipLaunchKernelGGL(transpose_w, dim3(32, 32, 4), dim3(256), 0, stream,
                       Wq, Wk, Wv, Wo, wqt, wkt, wvt, wot);
    hipLaunchKernelGGL(qkv_mfma, dim3(24, 32), dim3(256), 0, stream,
                       xb, wqt, wkt, wvt, bq, bk, bv, spW, sqW, vtW);
    hipLaunchKernelGGL(attn_mfma, dim3(32, 16), dim3(256), 0, stream,
                       spW, sqW, vtW, attB);
    hipLaunchKernelGGL(out_mfma, dim3(16, 32), dim3(256), 0, stream,
                       attB, wot, bo, out);
}

// Round 3
// 305.274 us; speedup vs baseline: 2.1046x; 1.0717x over previous
//
#include <hip/hip_runtime.h>
#include <math.h>

// GeoAttention on gfx950: B=2, S=2048, DIM=512, H=8, HD=64.
// All GEMM stages on bf16 MFMA (16x16x32), fp32 accumulate.
// attn: 8-wave blocks, 4-way j-split per 16-row group, partials combined in LDS.
// Score transform: bc in [0,1] (sp,sq >= 0), acos(x)^2 = Taylor in u=1-x (deg 8).

typedef __attribute__((ext_vector_type(8))) short short8;
typedef __attribute__((ext_vector_type(4))) float f32x4;

#define MFMA(a, b, c) __builtin_amdgcn_mfma_f32_16x16x32_bf16((a), (b), (c), 0, 0, 0)

static __device__ __forceinline__ short f2bf(float f) {
    unsigned u = __float_as_uint(f);
    u += 0x7fffu + ((u >> 16) & 1u);          // round-to-nearest-even
    return (short)(u >> 16);
}

// ---------------------------------------------------------------------------
// Prep 1: xb[4096][1024] bf16 = concat(x_real, x_imag)
// ---------------------------------------------------------------------------
__global__ __launch_bounds__(256) void convert_x(
    const float* __restrict__ xr, const float* __restrict__ xi,
    short* __restrict__ xb)
{
    int idx = blockIdx.x * 256 + threadIdx.x;   // 1,048,576 threads
    int e = idx << 2;
    int m = e >> 10, k = e & 1023;
    const float* src = (k < 512) ? xr : xi;
    float4 t = *(const float4*)(src + (size_t)m * 512 + (k & 511));
    unsigned lo = (unsigned short)f2bf(t.x) | ((unsigned)(unsigned short)f2bf(t.y) << 16);
    unsigned hi = (unsigned short)f2bf(t.z) | ((unsigned)(unsigned short)f2bf(t.w) << 16);
    uint2 o; o.x = lo; o.y = hi;
    *(uint2*)(xb + e) = o;
}

// ---------------------------------------------------------------------------
// Prep 2: transpose + convert weights to bf16, n-major [N][K].
// ---------------------------------------------------------------------------
__global__ __launch_bounds__(256) void transpose_w(
    const float* __restrict__ Wq, const float* __restrict__ Wk,
    const float* __restrict__ Wv, const float* __restrict__ Wo,
    short* __restrict__ wqt, short* __restrict__ wkt,
    short* __restrict__ wvt, short* __restrict__ wot)
{
    __shared__ float t[32][33];
    const int z = blockIdx.z;
    const float* src = (z == 0) ? Wq : (z == 1) ? Wk : (z == 2) ? Wv : Wo;
    short* dst = (z == 0) ? wqt : (z == 1) ? wkt : (z == 2) ? wvt : wot;
    const int K = (z < 3) ? 1024 : 512;
    const int N = (z < 3) ? 512 : 1024;
    const int n0 = blockIdx.x << 5, k0 = blockIdx.y << 5;
    if (n0 >= N || k0 >= K) return;
    const int tx = threadIdx.x & 31, ty = threadIdx.x >> 5;
    #pragma unroll
    for (int i = 0; i < 4; ++i)
        t[ty + 8 * i][tx] = src[(size_t)(k0 + ty + 8 * i) * N + n0 + tx];
    __syncthreads();
    #pragma unroll
    for (int i = 0; i < 4; ++i)
        dst[(size_t)(n0 + ty + 8 * i) * K + k0 + tx] = f2bf(t[tx][ty + 8 * i]);
}

// ---------------------------------------------------------------------------
// Kernel 1: QKV projection + fused softmax(64)+sqrt epilogue.
// Register-prefetched K-loop (distance 1).
// ---------------------------------------------------------------------------
__global__ __launch_bounds__(256) void qkv_mfma(
    const short* __restrict__ xb,
    const short* __restrict__ wqt, const short* __restrict__ wkt,
    const short* __restrict__ wvt,
    const float* __restrict__ bq, const float* __restrict__ bk,
    const float* __restrict__ bv,
    short* __restrict__ sp, short* __restrict__ sq, short* __restrict__ vt)
{
    const int iwb = blockIdx.x;
    const int iw = iwb >> 3;
    const int h  = iwb & 7;
    const int m0 = blockIdx.y << 7;
    const int tid = threadIdx.x;
    const int w = tid >> 6, lane = tid & 63;
    const int l = lane & 15, quad = lane >> 4;

    const short* wt   = (iw == 0) ? wqt : (iw == 1) ? wkt : wvt;
    const float* bias = (iw == 0) ? bq  : (iw == 1) ? bk  : bv;
    short* dst        = (iw == 0) ? sp  : (iw == 1) ? sq  : vt;

    const short* a0p = xb + (size_t)(m0 + w * 32 + l) * 1024 + quad * 8;
    const short* a1p = a0p + 16 * 1024;
    const short* bp0 = wt + (size_t)(h * 64 +  0 + l) * 1024 + quad * 8;
    const short* bp1 = wt + (size_t)(h * 64 + 16 + l) * 1024 + quad * 8;
    const short* bp2 = wt + (size_t)(h * 64 + 32 + l) * 1024 + quad * 8;
    const short* bp3 = wt + (size_t)(h * 64 + 48 + l) * 1024 + quad * 8;

    const f32x4 z4 = {0.f, 0.f, 0.f, 0.f};
    f32x4 acc[2][4];
    #pragma unroll
    for (int i = 0; i < 2; ++i)
        #pragma unroll
        for (int j = 0; j < 4; ++j) acc[i][j] = z4;

    short8 a0 = *(const short8*)(a0p), a1 = *(const short8*)(a1p);
    short8 b0 = *(const short8*)(bp0), b1 = *(const short8*)(bp1);
    short8 b2 = *(const short8*)(bp2), b3 = *(const short8*)(bp3);

    #pragma unroll 4
    for (int kc = 0; kc < 32; ++kc) {
        short8 na0, na1, nb0, nb1, nb2, nb3;
        const int ko = (kc + 1) * 32;
        if (kc < 31) {
            na0 = *(const short8*)(a0p + ko);
            na1 = *(const short8*)(a1p + ko);
            nb0 = *(const short8*)(bp0 + ko);
            nb1 = *(const short8*)(bp1 + ko);
            nb2 = *(const short8*)(bp2 + ko);
            nb3 = *(const short8*)(bp3 + ko);
        }
        acc[0][0] = MFMA(a0, b0, acc[0][0]);
        acc[1][0] = MFMA(a1, b0, acc[1][0]);
        acc[0][1] = MFMA(a0, b1, acc[0][1]);
        acc[1][1] = MFMA(a1, b1, acc[1][1]);
        acc[0][2] = MFMA(a0, b2, acc[0][2]);
        acc[1][2] = MFMA(a1, b2, acc[1][2]);
        acc[0][3] = MFMA(a0, b3, acc[0][3]);
        acc[1][3] = MFMA(a1, b3, acc[1][3]);
        if (kc < 31) { a0 = na0; a1 = na1; b0 = nb0; b1 = nb1; b2 = nb2; b3 = nb3; }
    }

    float bcol[4];
    #pragma unroll
    for (int nt = 0; nt < 4; ++nt) bcol[nt] = bias[h * 64 + nt * 16 + l];

    #pragma unroll
    for (int r16 = 0; r16 < 2; ++r16) {
        #pragma unroll
        for (int reg = 0; reg < 4; ++reg) {
            const int sg = m0 + w * 32 + r16 * 16 + quad * 4 + reg;  // global row
            const int b = sg >> 11, s = sg & 2047;
            float v[4];
            #pragma unroll
            for (int nt = 0; nt < 4; ++nt) v[nt] = acc[r16][nt][reg] + bcol[nt];
            if (iw < 2) {
                float mx = fmaxf(fmaxf(v[0], v[1]), fmaxf(v[2], v[3]));
                #pragma unroll
                for (int msk = 1; msk < 16; msk <<= 1) mx = fmaxf(mx, __shfl_xor(mx, msk));
                float e[4], ssum = 0.f;
                #pragma unroll
                for (int nt = 0; nt < 4; ++nt) { e[nt] = __expf(v[nt] - mx); ssum += e[nt]; }
                #pragma unroll
                for (int msk = 1; msk < 16; msk <<= 1) ssum += __shfl_xor(ssum, msk);
                float inv = 1.0f / ssum;
                short* o = dst + ((size_t)(b * 8 + h) * 2048 + s) * 64 + l;
                #pragma unroll
                for (int nt = 0; nt < 4; ++nt)
                    o[nt * 16] = f2bf(sqrtf(e[nt] * inv));
            } else {
                short* o = vt + ((size_t)(b * 8 + h) * 64 + l) * 2048 + s;
                #pragma unroll
                for (int nt = 0; nt < 4; ++nt)
                    o[(size_t)nt * 16 * 2048] = f2bf(v[nt]);
            }
        }
    }
}

// ---------------------------------------------------------------------------
// Kernel 2: attention. Grid (64, 16), 512 threads = 8 waves.
// Block covers 32 Q-rows: 2 row-groups x 4 j-splits (wave w: rg=w>>2, js=w&3).
// Each wave sweeps 512 j-columns (8 jt tiles of 64) accumulating partial
// numerator (MFMA acc) and denominator; partials combined in LDS at the end.
// No __syncthreads in the jt loop (wave-private LDS P slices).
// Transform: u=1-bc (bc>=0), d2 = Taylor(u) deg-8, w = exp(-d2).
// ---------------------------------------------------------------------------
__global__ __launch_bounds__(512) void attn_mfma(
    const short* __restrict__ sp, const short* __restrict__ sq,
    const short* __restrict__ vt, short* __restrict__ attB)
{
    __shared__ float Pb[8][16 * 68];            // per-wave 16x64 (+den col) fp32
    const int bh = blockIdx.y;
    const int tid = threadIdx.x;
    const int w = tid >> 6, lane = tid & 63;
    const int rg = w >> 2, js = w & 3;
    const int l = lane & 15, quad = lane >> 4;
    const int m0 = (blockIdx.x << 5) + rg * 16;

    const short* spB = sp + (size_t)bh * 2048 * 64;
    const short* sqB = sq + (size_t)bh * 2048 * 64 + (size_t)(js * 512) * 64;
    const short* vtB = vt + (size_t)bh * 64 * 2048 + js * 512;
    float* P = &Pb[w][0];

    const short* ap = spB + (size_t)(m0 + l) * 64 + quad * 8;
    short8 asp0 = *(const short8*)(ap);
    short8 asp1 = *(const short8*)(ap + 32);

    const f32x4 z4 = {0.f, 0.f, 0.f, 0.f};
    f32x4 acc[4] = {z4, z4, z4, z4};
    float den[4] = {0.f, 0.f, 0.f, 0.f};

    for (int jt = 0; jt < 8; ++jt) {
        const short* sqj = sqB + (size_t)(jt * 64) * 64;
        #pragma unroll
        for (int nt = 0; nt < 4; ++nt) {
            const short* q = sqj + (size_t)(nt * 16 + l) * 64 + quad * 8;
            short8 b0 = *(const short8*)(q);
            short8 b1 = *(const short8*)(q + 32);
            f32x4 p = MFMA(asp0, b0, z4);
            p = MFMA(asp1, b1, p);
            #pragma unroll
            for (int reg = 0; reg < 4; ++reg) {
                // bc in [0,1]; acos(x)^2 = 2u + u^2/3 + ... , u = 1-x
                float u = fmaxf(1.0f - p[reg], 0.0f);
                float t = 0.000922f;                    // c8 + tail compensation
                t = fmaf(t, u, 0.00152228f);
                t = fmaf(t, u, 0.00384801f);
                t = fmaf(t, u, 0.01015873f);
                t = fmaf(t, u, 0.02857143f);
                t = fmaf(t, u, 0.08888889f);
                t = fmaf(t, u, 0.33333333f);
                t = fmaf(t, u, 2.0f);
                float d2 = u * t;
                float wv = __expf(-d2);
                den[reg] += wv;
                P[(quad * 4 + reg) * 68 + nt * 16 + l] = wv;
            }
        }
        // P: C-layout (LDS) -> A-layout frags, bf16
        short8 pa0, pa1;
        {
            const float* pr = P + l * 68 + quad * 8;
            float4 f0 = *(const float4*)(pr);
            float4 f1 = *(const float4*)(pr + 4);
            float4 f2 = *(const float4*)(pr + 32);
            float4 f3 = *(const float4*)(pr + 36);
            pa0[0] = f2bf(f0.x); pa0[1] = f2bf(f0.y); pa0[2] = f2bf(f0.z); pa0[3] = f2bf(f0.w);
            pa0[4] = f2bf(f1.x); pa0[5] = f2bf(f1.y); pa0[6] = f2bf(f1.z); pa0[7] = f2bf(f1.w);
            pa1[0] = f2bf(f2.x); pa1[1] = f2bf(f2.y); pa1[2] = f2bf(f2.z); pa1[3] = f2bf(f2.w);
            pa1[4] = f2bf(f3.x); pa1[5] = f2bf(f3.y); pa1[6] = f2bf(f3.z); pa1[7] = f2bf(f3.w);
        }
        const short* vj = vtB + jt * 64;
        #pragma unroll
        for (int nt = 0; nt < 4; ++nt) {
            const short* q = vj + (size_t)(nt * 16 + l) * 2048 + quad * 8;
            short8 b0 = *(const short8*)(q);
            short8 b1 = *(const short8*)(q + 32);
            acc[nt] = MFMA(pa0, b0, acc[nt]);
            acc[nt] = MFMA(pa1, b1, acc[nt]);
        }
    }

    // per-wave: reduce den across the 16 l-lanes of each quad
    #pragma unroll
    for (int reg = 0; reg < 4; ++reg) {
        float s = den[reg];
        #pragma unroll
        for (int msk = 1; msk < 16; msk <<= 1) s += __shfl_xor(s, msk);
        den[reg] = s;
    }
    // dump partial numerator + denominator into this wave's LDS slice
    #pragma unroll
    for (int nt = 0; nt < 4; ++nt)
        #pragma unroll
        for (int reg = 0; reg < 4; ++reg)
            P[(quad * 4 + reg) * 68 + nt * 16 + l] = acc[nt][reg];
    if (l == 0) {
        #pragma unroll
        for (int reg = 0; reg < 4; ++reg) P[(quad * 4 + reg) * 68 + 64] = den[reg];
    }
    __syncthreads();

    // wave (rg*4+js) writes col-block js of row-group rg: sum the 4 partials
    const int b = bh >> 3, hh = bh & 7;
    #pragma unroll
    for (int reg = 0; reg < 4; ++reg) {
        const int row = quad * 4 + reg;
        float num = 0.f, dt = 0.f;
        #pragma unroll
        for (int s = 0; s < 4; ++s) {
            const float* sl = &Pb[rg * 4 + s][0];
            num += sl[row * 68 + js * 16 + l];
            dt  += sl[row * 68 + 64];
        }
        const int srow = m0 + row;
        attB[((size_t)(b * 2048 + srow)) * 512 + hh * 64 + js * 16 + l] =
            f2bf(num / dt);
    }
}

// ---------------------------------------------------------------------------
// Kernel 3: out = attB[4096][512](bf16) @ Wo + bo -> fp32, prefetched K-loop.
// ---------------------------------------------------------------------------
__global__ __launch_bounds__(256) void out_mfma(
    const short* __restrict__ attB, const short* __restrict__ wot,
    const float* __restrict__ bo, float* __restrict__ out)
{
    const int n0 = blockIdx.x << 6;
    const int m0 = blockIdx.y << 7;
    const int tid = threadIdx.x;
    const int w = tid >> 6, lane = tid & 63;
    const int l = lane & 15, quad = lane >> 4;

    const short* a0p = attB + (size_t)(m0 + w * 32 + l) * 512 + quad * 8;
    const short* a1p = a0p + 16 * 512;
    const short* bp0 = wot + (size_t)(n0 +  0 + l) * 512 + quad * 8;
    const short* bp1 = wot + (size_t)(n0 + 16 + l) * 512 + quad * 8;
    const short* bp2 = wot + (size_t)(n0 + 32 + l) * 512 + quad * 8;
    const short* bp3 = wot + (size_t)(n0 + 48 + l) * 512 + quad * 8;

    const f32x4 z4 = {0.f, 0.f, 0.f, 0.f};
    f32x4 acc[2][4];
    #pragma unroll
    for (int i = 0; i < 2; ++i)
        #pragma unroll
        for (int j = 0; j < 4; ++j) acc[i][j] = z4;

    short8 a0 = *(const short8*)(a0p), a1 = *(const short8*)(a1p);
    short8 b0 = *(const short8*)(bp0), b1 = *(const short8*)(bp1);
    short8 b2 = *(const short8*)(bp2), b3 = *(const short8*)(bp3);

    #pragma unroll 4
    for (int kc = 0; kc < 16; ++kc) {
        short8 na0, na1, nb0, nb1, nb2, nb3;
        const int ko = (kc + 1) * 32;
        if (kc < 15) {
            na0 = *(const short8*)(a0p + ko);
            na1 = *(const short8*)(a1p + ko);
            nb0 = *(const short8*)(bp0 + ko);
            nb1 = *(const short8*)(bp1 + ko);
            nb2 = *(const short8*)(bp2 + ko);
            nb3 = *(const short8*)(bp3 + ko);
        }
        acc[0][0] = MFMA(a0, b0, acc[0][0]);
        acc[1][0] = MFMA(a1, b0, acc[1][0]);
        acc[0][1] = MFMA(a0, b1, acc[0][1]);
        acc[1][1] = MFMA(a1, b1, acc[1][1]);
        acc[0][2] = MFMA(a0, b2, acc[0][2]);
        acc[1][2] = MFMA(a1, b2, acc[1][2]);
        acc[0][3] = MFMA(a0, b3, acc[0][3]);
        acc[1][3] = MFMA(a1, b3, acc[1][3]);
        if (kc < 15) { a0 = na0; a1 = na1; b0 = nb0; b1 = nb1; b2 = nb2; b3 = nb3; }
    }

    #pragma unroll
    for (int r16 = 0; r16 < 2; ++r16)
        #pragma unroll
        for (int reg = 0; reg < 4; ++reg) {
            const int m = m0 + w * 32 + r16 * 16 + quad * 4 + reg;
            float* o = out + (size_t)m * 1024 + n0 + l;
            #pragma unroll
            for (int nt = 0; nt < 4; ++nt)
                o[nt * 16] = acc[r16][nt][reg] + bo[n0 + nt * 16 + l];
        }
}

// ---------------------------------------------------------------------------
extern "C" void kernel_launch(void* const* d_in, const int* in_sizes, int n_in,
                              void* d_out, int out_size, void* d_ws, size_t ws_size,
                              hipStream_t stream) {
    const float* xr = (const float*)d_in[0];
    const float* xi = (const float*)d_in[1];
    const float* Wq = (const float*)d_in[2];
    const float* bq = (const float*)d_in[3];
    const float* Wk = (const float*)d_in[4];
    const float* bk = (const float*)d_in[5];
    const float* Wv = (const float*)d_in[6];
    const float* bv = (const float*)d_in[7];
    const float* Wo = (const float*)d_in[8];
    const float* bo = (const float*)d_in[9];
    float* out = (float*)d_out;

    short* base = (short*)d_ws;
    short* xb   = base;                      // 4096*1024
    short* wqt  = xb  + 4194304;             // 512*1024
    short* wkt  = wqt + 524288;
    short* wvt  = wkt + 524288;
    short* wot  = wvt + 524288;              // 1024*512
    short* spW  = wot + 524288;              // 16*2048*64
    short* sqW  = spW + 2097152;
    short* vtW  = sqW + 2097152;             // [b,h,d,s]
    short* attB = vtW + 2097152;             // 4096*512
    // total = 14,680,064 shorts = 28 MB

    hipLaunchKernelGGL(convert_x, dim3(4096), dim3(256), 0, stream, xr, xi, xb);
    hipLaunchKernelGGL(transpose_w, dim3(32, 32, 4), dim3(256), 0, stream,
                       Wq, Wk, Wv, Wo, wqt, wkt, wvt, wot);
    hipLaunchKernelGGL(qkv_mfma, dim3(24, 32), dim3(256), 0, stream,
                       xb, wqt, wkt, wvt, bq, bk, bv, spW, sqW, vtW);
    hipLaunchKernelGGL(attn_mfma, dim3(64, 16), dim3(512), 0, stream,
                       spW, sqW, vtW, attB);
    hipLaunchKernelGGL(out_mfma, dim3(16, 32), dim3(256), 0, stream,
                       attB, wot, bo, out);
}

// Round 4
// 251.157 us; speedup vs baseline: 2.5581x; 1.2155x over previous
//
#include <hip/hip_runtime.h>
#include <math.h>

// GeoAttention on gfx950: B=2, S=2048, DIM=512, H=8, HD=64.
// All GEMM stages on bf16 MFMA (16x16x32), fp32 accumulate, operands read as
// contiguous 16B frags from global bf16 (no LDS in GEMM main loops).
// attn: 8-wave blocks, wave = 32 Q-rows x 4-way j-split; bf16 P-transform
// slices in LDS (stride 72 shorts -> direct short8 A-frag reads).

typedef __attribute__((ext_vector_type(8))) short short8;
typedef __attribute__((ext_vector_type(4))) float f32x4;

#define MFMA(a, b, c) __builtin_amdgcn_mfma_f32_16x16x32_bf16((a), (b), (c), 0, 0, 0)

static __device__ __forceinline__ short f2bf(float f) {
    unsigned u = __float_as_uint(f);
    u += 0x7fffu + ((u >> 16) & 1u);          // round-to-nearest-even
    return (short)(u >> 16);
}

// ---------------------------------------------------------------------------
// Prep 1: xb[4096][1024] bf16 = concat(x_real, x_imag)
// ---------------------------------------------------------------------------
__global__ __launch_bounds__(256) void convert_x(
    const float* __restrict__ xr, const float* __restrict__ xi,
    short* __restrict__ xb)
{
    int idx = blockIdx.x * 256 + threadIdx.x;
    int e = idx << 2;
    int m = e >> 10, k = e & 1023;
    const float* src = (k < 512) ? xr : xi;
    float4 t = *(const float4*)(src + (size_t)m * 512 + (k & 511));
    unsigned lo = (unsigned short)f2bf(t.x) | ((unsigned)(unsigned short)f2bf(t.y) << 16);
    unsigned hi = (unsigned short)f2bf(t.z) | ((unsigned)(unsigned short)f2bf(t.w) << 16);
    uint2 o; o.x = lo; o.y = hi;
    *(uint2*)(xb + e) = o;
}

// ---------------------------------------------------------------------------
// Prep 2: transpose + convert weights to bf16, n-major [N][K].
// ---------------------------------------------------------------------------
__global__ __launch_bounds__(256) void transpose_w(
    const float* __restrict__ Wq, const float* __restrict__ Wk,
    const float* __restrict__ Wv, const float* __restrict__ Wo,
    short* __restrict__ wqt, short* __restrict__ wkt,
    short* __restrict__ wvt, short* __restrict__ wot)
{
    __shared__ float t[32][33];
    const int z = blockIdx.z;
    const float* src = (z == 0) ? Wq : (z == 1) ? Wk : (z == 2) ? Wv : Wo;
    short* dst = (z == 0) ? wqt : (z == 1) ? wkt : (z == 2) ? wvt : wot;
    const int K = (z < 3) ? 1024 : 512;
    const int N = (z < 3) ? 512 : 1024;
    const int n0 = blockIdx.x << 5, k0 = blockIdx.y << 5;
    if (n0 >= N || k0 >= K) return;
    const int tx = threadIdx.x & 31, ty = threadIdx.x >> 5;
    #pragma unroll
    for (int i = 0; i < 4; ++i)
        t[ty + 8 * i][tx] = src[(size_t)(k0 + ty + 8 * i) * N + n0 + tx];
    __syncthreads();
    #pragma unroll
    for (int i = 0; i < 4; ++i)
        dst[(size_t)(n0 + ty + 8 * i) * K + k0 + tx] = f2bf(t[tx][ty + 8 * i]);
}

// ---------------------------------------------------------------------------
// Kernel 1: QKV projection + fused softmax(64)+sqrt epilogue.
// V written transposed [b,h,d,s] via wave-private LDS bounce (coalesced-ish:
// 16B/lane stores instead of the old 2B x 4KB-stride scatter).
// ---------------------------------------------------------------------------
__global__ __launch_bounds__(256) void qkv_mfma(
    const short* __restrict__ xb,
    const short* __restrict__ wqt, const short* __restrict__ wkt,
    const short* __restrict__ wvt,
    const float* __restrict__ bq, const float* __restrict__ bk,
    const float* __restrict__ bv,
    short* __restrict__ sp, short* __restrict__ sq, short* __restrict__ vt)
{
    __shared__ short vbuf[4][64 * 40];        // per-wave [d=64][s=32 +pad8]
    const int iwb = blockIdx.x;
    const int iw = iwb >> 3;
    const int h  = iwb & 7;
    const int m0 = blockIdx.y << 7;
    const int tid = threadIdx.x;
    const int w = tid >> 6, lane = tid & 63;
    const int l = lane & 15, quad = lane >> 4;

    const short* wt   = (iw == 0) ? wqt : (iw == 1) ? wkt : wvt;
    const float* bias = (iw == 0) ? bq  : (iw == 1) ? bk  : bv;
    short* dst        = (iw == 0) ? sp  : (iw == 1) ? sq  : vt;

    const short* a0p = xb + (size_t)(m0 + w * 32 + l) * 1024 + quad * 8;
    const short* a1p = a0p + 16 * 1024;
    const short* bp0 = wt + (size_t)(h * 64 +  0 + l) * 1024 + quad * 8;
    const short* bp1 = wt + (size_t)(h * 64 + 16 + l) * 1024 + quad * 8;
    const short* bp2 = wt + (size_t)(h * 64 + 32 + l) * 1024 + quad * 8;
    const short* bp3 = wt + (size_t)(h * 64 + 48 + l) * 1024 + quad * 8;

    const f32x4 z4 = {0.f, 0.f, 0.f, 0.f};
    f32x4 acc[2][4];
    #pragma unroll
    for (int i = 0; i < 2; ++i)
        #pragma unroll
        for (int j = 0; j < 4; ++j) acc[i][j] = z4;

    for (int kc = 0; kc < 32; ++kc) {
        const int ko = kc * 32;
        short8 a0 = *(const short8*)(a0p + ko);
        short8 a1 = *(const short8*)(a1p + ko);
        short8 b0 = *(const short8*)(bp0 + ko);
        short8 b1 = *(const short8*)(bp1 + ko);
        short8 b2 = *(const short8*)(bp2 + ko);
        short8 b3 = *(const short8*)(bp3 + ko);
        acc[0][0] = MFMA(a0, b0, acc[0][0]);
        acc[1][0] = MFMA(a1, b0, acc[1][0]);
        acc[0][1] = MFMA(a0, b1, acc[0][1]);
        acc[1][1] = MFMA(a1, b1, acc[1][1]);
        acc[0][2] = MFMA(a0, b2, acc[0][2]);
        acc[1][2] = MFMA(a1, b2, acc[1][2]);
        acc[0][3] = MFMA(a0, b3, acc[0][3]);
        acc[1][3] = MFMA(a1, b3, acc[1][3]);
    }

    float bcol[4];
    #pragma unroll
    for (int nt = 0; nt < 4; ++nt) bcol[nt] = bias[h * 64 + nt * 16 + l];

    #pragma unroll
    for (int r16 = 0; r16 < 2; ++r16) {
        #pragma unroll
        for (int reg = 0; reg < 4; ++reg) {
            const int sg = m0 + w * 32 + r16 * 16 + quad * 4 + reg;  // global row
            const int b = sg >> 11, s = sg & 2047;
            float v[4];
            #pragma unroll
            for (int nt = 0; nt < 4; ++nt) v[nt] = acc[r16][nt][reg] + bcol[nt];
            if (iw < 2) {
                float mx = fmaxf(fmaxf(v[0], v[1]), fmaxf(v[2], v[3]));
                #pragma unroll
                for (int msk = 1; msk < 16; msk <<= 1) mx = fmaxf(mx, __shfl_xor(mx, msk));
                float e[4], ssum = 0.f;
                #pragma unroll
                for (int nt = 0; nt < 4; ++nt) { e[nt] = __expf(v[nt] - mx); ssum += e[nt]; }
                #pragma unroll
                for (int msk = 1; msk < 16; msk <<= 1) ssum += __shfl_xor(ssum, msk);
                float inv = 1.0f / ssum;
                short* o = dst + ((size_t)(b * 8 + h) * 2048 + s) * 64 + l;
                #pragma unroll
                for (int nt = 0; nt < 4; ++nt)
                    o[nt * 16] = f2bf(sqrtf(e[nt] * inv));
            } else {
                const int sl = r16 * 16 + quad * 4 + reg;   // local s in [0,32)
                #pragma unroll
                for (int nt = 0; nt < 4; ++nt)
                    vbuf[w][(nt * 16 + l) * 40 + sl] = f2bf(v[nt]);
            }
        }
    }

    if (iw == 2) {
        // wave-synchronous readback: lane d -> 32 contiguous s, 16B stores
        const int d = lane;
        const short* row = &vbuf[w][d * 40];
        short8 r0 = *(const short8*)(row);
        short8 r1 = *(const short8*)(row + 8);
        short8 r2 = *(const short8*)(row + 16);
        short8 r3 = *(const short8*)(row + 24);
        const int sg0 = m0 + w * 32;
        const int b = sg0 >> 11, s0 = sg0 & 2047;
        short* gp = vt + ((size_t)(b * 8 + h) * 64 + d) * 2048 + s0;
        *(short8*)(gp)      = r0;
        *(short8*)(gp + 8)  = r1;
        *(short8*)(gp + 16) = r2;
        *(short8*)(gp + 24) = r3;
    }
}

// ---------------------------------------------------------------------------
// Kernel 2: attention. Grid (32, 16), 512 threads = 8 waves.
// Block = 64 Q-rows: wave w -> rowgroup rg=w>>2 (32 rows), j-split js=w&3
// (512 j-cols each). No __syncthreads in the jt loop (wave-private LDS).
// P-transform slice stored as bf16 stride-72 -> direct short8 A-frag reads.
// Epilogue: two barrier-phased fp32 combines reusing the Ps buffer.
// ---------------------------------------------------------------------------
__global__ __launch_bounds__(512) void attn_mfma(
    const short* __restrict__ sp, const short* __restrict__ sq,
    const short* __restrict__ vt, short* __restrict__ attB)
{
    __shared__ short Ps[8][32 * 72];            // 36,864 B
    __shared__ float denB[8][32];               // 1 KB
    const int bh = blockIdx.y;
    const int tid = threadIdx.x;
    const int w = tid >> 6, lane = tid & 63;
    const int rg = w >> 2, js = w & 3;
    const int l = lane & 15, quad = lane >> 4;
    const int m0 = (blockIdx.x << 6) + rg * 32;

    const short* spB = sp + (size_t)bh * 2048 * 64;
    const short* sqB = sq + (size_t)bh * 2048 * 64 + (size_t)(js * 512) * 64;
    const short* vtB = vt + (size_t)bh * 64 * 2048 + js * 512;
    short* P = &Ps[w][0];

    const short* ap0 = spB + (size_t)(m0 + l) * 64 + quad * 8;
    const short* ap1 = spB + (size_t)(m0 + 16 + l) * 64 + quad * 8;
    short8 a00 = *(const short8*)(ap0);
    short8 a01 = *(const short8*)(ap0 + 32);
    short8 a10 = *(const short8*)(ap1);
    short8 a11 = *(const short8*)(ap1 + 32);

    const f32x4 z4 = {0.f, 0.f, 0.f, 0.f};
    f32x4 acc[2][4];
    float den[2][4];
    #pragma unroll
    for (int s = 0; s < 2; ++s)
        #pragma unroll
        for (int j = 0; j < 4; ++j) { acc[s][j] = z4; den[s][j] = 0.f; }

    for (int jt = 0; jt < 8; ++jt) {
        const short* sqj = sqB + (size_t)(jt * 64) * 64;
        #pragma unroll
        for (int nt = 0; nt < 4; ++nt) {
            const short* q = sqj + (size_t)(nt * 16 + l) * 64 + quad * 8;
            short8 b0 = *(const short8*)(q);
            short8 b1 = *(const short8*)(q + 32);
            #pragma unroll
            for (int s = 0; s < 2; ++s) {
                f32x4 p = MFMA(s ? a10 : a00, b0, z4);
                p = MFMA(s ? a11 : a01, b1, p);
                #pragma unroll
                for (int reg = 0; reg < 4; ++reg) {
                    // bc in [0,1]; acos(x)^2 = 2u + u^2/3 + ..., u = 1-x
                    float u = fmaxf(1.0f - p[reg], 0.0f);
                    float t = 0.000922f;
                    t = fmaf(t, u, 0.00152228f);
                    t = fmaf(t, u, 0.00384801f);
                    t = fmaf(t, u, 0.01015873f);
                    t = fmaf(t, u, 0.02857143f);
                    t = fmaf(t, u, 0.08888889f);
                    t = fmaf(t, u, 0.33333333f);
                    t = fmaf(t, u, 2.0f);
                    float d2 = u * t;
                    float wv = __expf(-d2);
                    den[s][reg] += wv;
                    P[(s * 16 + quad * 4 + reg) * 72 + nt * 16 + l] = f2bf(wv);
                }
            }
        }
        // P rows -> A-frags (bf16, stride-72 rows are 16B aligned)
        short8 pa[2][2];
        #pragma unroll
        for (int s = 0; s < 2; ++s) {
            const short* pr = P + (s * 16 + l) * 72 + quad * 8;
            pa[s][0] = *(const short8*)(pr);
            pa[s][1] = *(const short8*)(pr + 32);
        }
        const short* vj = vtB + jt * 64;
        #pragma unroll
        for (int nt = 0; nt < 4; ++nt) {
            const short* q = vj + (size_t)(nt * 16 + l) * 2048 + quad * 8;
            short8 b0 = *(const short8*)(q);
            short8 b1 = *(const short8*)(q + 32);
            #pragma unroll
            for (int s = 0; s < 2; ++s) {
                acc[s][nt] = MFMA(pa[s][0], b0, acc[s][nt]);
                acc[s][nt] = MFMA(pa[s][1], b1, acc[s][nt]);
            }
        }
    }

    // reduce den over the 16 l-lanes of each quad; store per-wave
    #pragma unroll
    for (int s = 0; s < 2; ++s)
        #pragma unroll
        for (int reg = 0; reg < 4; ++reg) {
            float sm = den[s][reg];
            #pragma unroll
            for (int msk = 1; msk < 16; msk <<= 1) sm += __shfl_xor(sm, msk);
            if (l == 0) denB[w][s * 16 + quad * 4 + reg] = sm;
        }

    __syncthreads();
    // two-phase fp32 combine reusing Ps memory (4 x 2176 floats = 34.8 KB)
    float* Cb = (float*)&Ps[0][0];
    const int b = bh >> 3, hh = bh & 7;
    #pragma unroll
    for (int ph = 0; ph < 2; ++ph) {
        if (rg == ph) {
            float* Cw = Cb + js * 2176;
            #pragma unroll
            for (int s = 0; s < 2; ++s)
                #pragma unroll
                for (int nt = 0; nt < 4; ++nt)
                    #pragma unroll
                    for (int reg = 0; reg < 4; ++reg)
                        Cw[(s * 16 + quad * 4 + reg) * 68 + nt * 16 + l] = acc[s][nt][reg];
        }
        __syncthreads();
        if (rg == ph) {
            #pragma unroll
            for (int half = 0; half < 2; ++half)
                #pragma unroll
                for (int reg = 0; reg < 4; ++reg) {
                    const int row = half * 16 + quad * 4 + reg;
                    float num = 0.f, dt = 0.f;
                    #pragma unroll
                    for (int s2 = 0; s2 < 4; ++s2) {
                        num += Cb[s2 * 2176 + row * 68 + js * 16 + l];
                        dt  += denB[rg * 4 + s2][row];
                    }
                    const int srow = (blockIdx.x << 6) + rg * 32 + row;
                    attB[((size_t)(b * 2048 + srow)) * 512 + hh * 64 + js * 16 + l] =
                        f2bf(num / dt);
                }
        }
        __syncthreads();
    }
}

// ---------------------------------------------------------------------------
// Kernel 3: out = attB[4096][512](bf16) @ Wo + bo -> fp32 [4096][1024]
// ---------------------------------------------------------------------------
__global__ __launch_bounds__(256) void out_mfma(
    const short* __restrict__ attB, const short* __restrict__ wot,
    const float* __restrict__ bo, float* __restrict__ out)
{
    const int n0 = blockIdx.x << 6;
    const int m0 = blockIdx.y << 7;
    const int tid = threadIdx.x;
    const int w = tid >> 6, lane = tid & 63;
    const int l = lane & 15, quad = lane >> 4;

    const short* a0p = attB + (size_t)(m0 + w * 32 + l) * 512 + quad * 8;
    const short* a1p = a0p + 16 * 512;
    const short* bp0 = wot + (size_t)(n0 +  0 + l) * 512 + quad * 8;
    const short* bp1 = wot + (size_t)(n0 + 16 + l) * 512 + quad * 8;
    const short* bp2 = wot + (size_t)(n0 + 32 + l) * 512 + quad * 8;
    const short* bp3 = wot + (size_t)(n0 + 48 + l) * 512 + quad * 8;

    const f32x4 z4 = {0.f, 0.f, 0.f, 0.f};
    f32x4 acc[2][4];
    #pragma unroll
    for (int i = 0; i < 2; ++i)
        #pragma unroll
        for (int j = 0; j < 4; ++j) acc[i][j] = z4;

    for (int kc = 0; kc < 16; ++kc) {
        const int ko = kc * 32;
        short8 a0 = *(const short8*)(a0p + ko);
        short8 a1 = *(const short8*)(a1p + ko);
        short8 b0 = *(const short8*)(bp0 + ko);
        short8 b1 = *(const short8*)(bp1 + ko);
        short8 b2 = *(const short8*)(bp2 + ko);
        short8 b3 = *(const short8*)(bp3 + ko);
        acc[0][0] = MFMA(a0, b0, acc[0][0]);
        acc[1][0] = MFMA(a1, b0, acc[1][0]);
        acc[0][1] = MFMA(a0, b1, acc[0][1]);
        acc[1][1] = MFMA(a1, b1, acc[1][1]);
        acc[0][2] = MFMA(a0, b2, acc[0][2]);
        acc[1][2] = MFMA(a1, b2, acc[1][2]);
        acc[0][3] = MFMA(a0, b3, acc[0][3]);
        acc[1][3] = MFMA(a1, b3, acc[1][3]);
    }

    #pragma unroll
    for (int r16 = 0; r16 < 2; ++r16)
        #pragma unroll
        for (int reg = 0; reg < 4; ++reg) {
            const int m = m0 + w * 32 + r16 * 16 + quad * 4 + reg;
            float* o = out + (size_t)m * 1024 + n0 + l;
            #pragma unroll
            for (int nt = 0; nt < 4; ++nt)
                o[nt * 16] = acc[r16][nt][reg] + bo[n0 + nt * 16 + l];
        }
}

// ---------------------------------------------------------------------------
extern "C" void kernel_launch(void* const* d_in, const int* in_sizes, int n_in,
                              void* d_out, int out_size, void* d_ws, size_t ws_size,
                              hipStream_t stream) {
    const float* xr = (const float*)d_in[0];
    const float* xi = (const float*)d_in[1];
    const float* Wq = (const float*)d_in[2];
    const float* bq = (const float*)d_in[3];
    const float* Wk = (const float*)d_in[4];
    const float* bk = (const float*)d_in[5];
    const float* Wv = (const float*)d_in[6];
    const float* bv = (const float*)d_in[7];
    const float* Wo = (const float*)d_in[8];
    const float* bo = (const float*)d_in[9];
    float* out = (float*)d_out;

    short* base = (short*)d_ws;
    short* xb   = base;                      // 4096*1024
    short* wqt  = xb  + 4194304;             // 512*1024
    short* wkt  = wqt + 524288;
    short* wvt  = wkt + 524288;
    short* wot  = wvt + 524288;              // 1024*512
    short* spW  = wot + 524288;              // 16*2048*64
    short* sqW  = spW + 2097152;
    short* vtW  = sqW + 2097152;             // [b,h,d,s]
    short* attB = vtW + 2097152;             // 4096*512
    // total = 14,680,064 shorts = 28 MB

    hipLaunchKernelGGL(convert_x, dim3(4096), dim3(256), 0, stream, xr, xi, xb);
    hipLaunchKernelGGL(transpose_w, dim3(32, 32, 4), dim3(256), 0, stream,
                       Wq, Wk, Wv, Wo, wqt, wkt, wvt, wot);
    hipLaunchKernelGGL(qkv_mfma, dim3(24, 32), dim3(256), 0, stream,
                       xb, wqt, wkt, wvt, bq, bk, bv, spW, sqW, vtW);
    hipLaunchKernelGGL(attn_mfma, dim3(32, 16), dim3(512), 0, stream,
                       spW, sqW, vtW, attB);
    hipLaunchKernelGGL(out_mfma, dim3(16, 32), dim3(256), 0, stream,
                       attB, wot, bo, out);
}